// Round 1
// baseline (17.664 us; speedup 1.0000x reference)
//
#include <hip/hip_runtime.h>

// Problem constants (from reference): x [B=128, IN=1024] f32,
// layer_mask [OUT=1024, IN=1024] f32 (binary, ~5% dense), out [B, OUT] f32.
#define B_SZ   128
#define OUT_SZ 1024
#define IN_SZ  1024

// ---------------------------------------------------------------------------
// Kernel 1: transpose x [B, IN] -> xT [IN, B] so column gathers coalesce.
// Grid (IN/32, B/32), block (32, 8). Standard LDS tile transpose, +1 pad.
// ---------------------------------------------------------------------------
__global__ __launch_bounds__(256) void transpose_x(const float* __restrict__ in,
                                                   float* __restrict__ out) {
    __shared__ float tile[32][33];
    const int c0 = blockIdx.x * 32;   // column in x  (IN dim)
    const int r0 = blockIdx.y * 32;   // row    in x  (B dim)
    const int tx = threadIdx.x, ty = threadIdx.y;
#pragma unroll
    for (int j = ty; j < 32; j += 8)
        tile[j][tx] = in[(r0 + j) * IN_SZ + c0 + tx];
    __syncthreads();
#pragma unroll
    for (int j = ty; j < 32; j += 8)
        out[(c0 + j) * B_SZ + r0 + tx] = tile[tx][j];
}

// ---------------------------------------------------------------------------
// Kernel 2: one block per output row o. Phase A: compact the nonzero columns
// of mask[o,:] into LDS (deterministic order via prefix sum, so the FP
// product order matches the reference's left-to-right order). Phase B:
// thread t = batch b walks the index list.
// xT may be null (ws too small fallback) -> strided reads of x directly.
// ---------------------------------------------------------------------------
__global__ __launch_bounds__(128) void cn_update(const float* __restrict__ xT,
                                                 const float* __restrict__ x,
                                                 const float* __restrict__ mask,
                                                 float* __restrict__ out) {
    __shared__ int   s_idx[IN_SZ];
    __shared__ float s_val[IN_SZ];
    __shared__ int   s_cnt[B_SZ + 1];

    const int o = blockIdx.x;
    const int t = threadIdx.x;

    // --- Phase A: scan 8 contiguous mask entries per thread (2x float4) ---
    const int base = o * IN_SZ + t * 8;
    const float4 m0 = *reinterpret_cast<const float4*>(mask + base);
    const float4 m1 = *reinterpret_cast<const float4*>(mask + base + 4);
    float mv[8] = {m0.x, m0.y, m0.z, m0.w, m1.x, m1.y, m1.z, m1.w};

    int c = 0;
#pragma unroll
    for (int j = 0; j < 8; ++j) c += (mv[j] != 0.0f);
    s_cnt[t] = c;
    __syncthreads();

    if (t == 0) {  // serial exclusive scan over 128 counts (cheap, deterministic)
        int acc = 0;
        for (int i = 0; i < B_SZ; ++i) { int v = s_cnt[i]; s_cnt[i] = acc; acc += v; }
        s_cnt[B_SZ] = acc;
    }
    __syncthreads();

    int off = s_cnt[t];
#pragma unroll
    for (int j = 0; j < 8; ++j) {
        if (mv[j] != 0.0f) { s_idx[off] = t * 8 + j; s_val[off] = mv[j]; ++off; }
    }
    const int cnt = s_cnt[B_SZ];
    __syncthreads();

    // --- Phase B: thread t = batch b; product over the compacted columns ---
    float prod = 1.0f;
    bool  any  = false;
    if (xT != nullptr) {
        for (int k = 0; k < cnt; ++k) {
            // s_idx[k]/s_val[k]: same LDS address for all lanes -> broadcast.
            // xT row read: 128 consecutive floats -> fully coalesced.
            float v = xT[s_idx[k] * B_SZ + t] * s_val[k];
            if (v != 0.0f) { prod *= v; any = true; }
        }
    } else {
        for (int k = 0; k < cnt; ++k) {
            float v = x[t * IN_SZ + s_idx[k]] * s_val[k];
            if (v != 0.0f) { prod *= v; any = true; }
        }
    }

    out[t * OUT_SZ + o] = any ? prod : 0.0f;
}

// ---------------------------------------------------------------------------
extern "C" void kernel_launch(void* const* d_in, const int* in_sizes, int n_in,
                              void* d_out, int out_size, void* d_ws, size_t ws_size,
                              hipStream_t stream) {
    const float* x    = (const float*)d_in[0];
    const float* mask = (const float*)d_in[1];
    float*       out  = (float*)d_out;

    const size_t xt_bytes = (size_t)B_SZ * IN_SZ * sizeof(float);
    float* xT = nullptr;
    if (ws_size >= xt_bytes) {
        xT = (float*)d_ws;
        dim3 g(IN_SZ / 32, B_SZ / 32), b(32, 8);
        transpose_x<<<g, b, 0, stream>>>(x, xT);
    }

    cn_update<<<OUT_SZ, B_SZ, 0, stream>>>(xT, x, mask, out);
}

// Round 2
// 17.202 us; speedup vs baseline: 1.0269x; 1.0269x over previous
//
#include <hip/hip_runtime.h>

// x [B=128, IN=1024] f32, layer_mask [OUT=1024, IN=1024] f32 (exactly 0.0/1.0,
// ~5% dense), out [B, OUT] f32.  out[b,o] = prod_{i: mask[o,i]!=0, x[b,i]!=0} x[b,i],
// or 0 if no nonzero masked term. Mask is binary => multiplying by mask value is
// a no-op; FP reorder is fine (threshold 2.7e-2 absolute >> f32 reorder error).
#define B_SZ   128
#define OUT_SZ 1024
#define IN_SZ  1024

// ---------------------------------------------------------------------------
// Kernel 1: transpose x [B, IN] -> xT [IN, B] so per-index batch reads coalesce.
// ---------------------------------------------------------------------------
__global__ __launch_bounds__(256) void transpose_x(const float* __restrict__ in,
                                                   float* __restrict__ out) {
    __shared__ float tile[32][33];
    const int c0 = blockIdx.x * 32;   // IN dim
    const int r0 = blockIdx.y * 32;   // B dim
    const int tx = threadIdx.x, ty = threadIdx.y;
#pragma unroll
    for (int j = ty; j < 32; j += 8)
        tile[j][tx] = in[(r0 + j) * IN_SZ + c0 + tx];
    __syncthreads();
#pragma unroll
    for (int j = ty; j < 32; j += 8)
        out[(c0 + j) * B_SZ + r0 + tx] = tile[tx][j];
}

// ---------------------------------------------------------------------------
// Kernel 2: one block (512 thr = 8 waves) per output row o.
//  Phase A: ballot-compact nonzero mask columns into s_idx (no serial scan).
//  Phase B: thread (b = t&127, s = t>>7) takes k = s, s+4, ... -> ~13 iters.
//  Combine 4 partial products per batch via LDS.
// ---------------------------------------------------------------------------
__global__ __launch_bounds__(512) void cn_update(const float* __restrict__ xT,
                                                 const float* __restrict__ mask,
                                                 float* __restrict__ out) {
    __shared__ int   s_idx[IN_SZ];
    __shared__ int   s_wsum[8];
    __shared__ float s_part[4][B_SZ];
    __shared__ int   s_nz[4][B_SZ];

    const int o    = blockIdx.x;
    const int t    = threadIdx.x;
    const int lane = t & 63;
    const int wv   = t >> 6;   // 0..7

    // --- Phase A: each thread scans 2 mask entries; ballot-based compaction ---
    const float2 m = *reinterpret_cast<const float2*>(mask + o * IN_SZ + t * 2);
    const bool nx = (m.x != 0.0f);
    const bool ny = (m.y != 0.0f);
    const unsigned long long bx = __ballot(nx);
    const unsigned long long by = __ballot(ny);
    const unsigned long long mlow = ((unsigned long long)1 << lane) - 1;
    int off_x = __popcll(bx & mlow) + __popcll(by & mlow);  // within-wave excl offset
    if (lane == 0) s_wsum[wv] = __popcll(bx) + __popcll(by);
    __syncthreads();

    int base = 0, cnt = 0;
#pragma unroll
    for (int i = 0; i < 8; ++i) {   // broadcast reads, 8 waves
        int v = s_wsum[i];
        if (i < wv) base += v;
        cnt += v;
    }
    off_x += base;
    if (nx) s_idx[off_x]      = t * 2;
    if (ny) s_idx[off_x + nx] = t * 2 + 1;
    __syncthreads();

    // --- Phase B: strided partial products over the compacted index list ---
    const int b = t & 127;   // batch
    const int s = t >> 7;    // k-slice 0..3 (wave-uniform)
    float prod = 1.0f;
    int   any  = 0;
    for (int k = s; k < cnt; k += 4) {
        // s_idx[k]: wave-uniform broadcast. xT row chunk: 64 lanes x 4B coalesced.
        const float v = xT[s_idx[k] * B_SZ + b];
        const bool nz = (v != 0.0f);
        prod *= nz ? v : 1.0f;
        any  |= nz;
    }
    s_part[s][b] = prod;
    s_nz[s][b]   = any;
    __syncthreads();

    if (t < B_SZ) {
        const float p = s_part[0][t] * s_part[1][t] * s_part[2][t] * s_part[3][t];
        const int   a = s_nz[0][t] | s_nz[1][t] | s_nz[2][t] | s_nz[3][t];
        out[t * OUT_SZ + o] = a ? p : 0.0f;
    }
}

// ---------------------------------------------------------------------------
extern "C" void kernel_launch(void* const* d_in, const int* in_sizes, int n_in,
                              void* d_out, int out_size, void* d_ws, size_t ws_size,
                              hipStream_t stream) {
    const float* x    = (const float*)d_in[0];
    const float* mask = (const float*)d_in[1];
    float*       out  = (float*)d_out;

    float* xT = (float*)d_ws;   // 512 KB; ws is guaranteed scratch
    {
        dim3 g(IN_SZ / 32, B_SZ / 32), b(32, 8);
        transpose_x<<<g, b, 0, stream>>>(x, xT);
    }
    cn_update<<<OUT_SZ, B_SZ * 4, 0, stream>>>(xT, mask, out);
}

// Round 3
// 15.432 us; speedup vs baseline: 1.1447x; 1.1147x over previous
//
#include <hip/hip_runtime.h>

// x [B=128, IN=1024] f32, layer_mask [OUT=1024, IN=1024] f32 (exactly 0.0/1.0,
// ~5% dense), out [B, OUT] f32.  out[b,o] = prod over {i: mask[o,i]!=0, x[b,i]!=0}
// of x[b,i]; 0 if no nonzero masked term. Mask binary => its value multiply is a
// no-op. FP reorder fine (threshold 2.7e-2 absolute >> f32 reorder error).
#define B_SZ   128
#define OUT_SZ 1024
#define IN_SZ  1024
#define IDX_STRIDE 1024   // worst-case nnz per row (can't overflow)

// ws layout: [0,512K) xT[IN][B] ; [512K,516K) cnt[OUT] ; [1M,5M) idx[OUT][IDX_STRIDE]

// ---------------------------------------------------------------------------
// Kernel 1 (dual role, one dispatch so both roles run concurrently):
//  blocks [0, OUT_SZ): ballot-compact nonzero columns of mask row o -> CSR.
//  blocks [OUT_SZ, OUT_SZ+128): 32x32 tile transpose of x -> xT.
// Neither role depends on the other.
// ---------------------------------------------------------------------------
__global__ __launch_bounds__(512) void prep(const float* __restrict__ x,
                                            const float* __restrict__ mask,
                                            float* __restrict__ xT,
                                            int* __restrict__ g_cnt,
                                            int* __restrict__ g_idx) {
    __shared__ int   s_idx[IN_SZ];
    __shared__ int   s_wsum[8];
    __shared__ float s_tile[32][33];

    const int t = threadIdx.x;

    if (blockIdx.x >= OUT_SZ) {
        // ---- transpose role ----
        const int tb = blockIdx.x - OUT_SZ;   // 0..127
        const int c0 = (tb & 31) * 32;        // IN dim
        const int r0 = (tb >> 5) * 32;        // B dim
        const int tx = t & 31, ty = t >> 5;   // 32 x 16
#pragma unroll
        for (int j = ty; j < 32; j += 16)
            s_tile[j][tx] = x[(r0 + j) * IN_SZ + c0 + tx];
        __syncthreads();
#pragma unroll
        for (int j = ty; j < 32; j += 16)
            xT[(c0 + j) * B_SZ + r0 + tx] = s_tile[tx][j];
        return;
    }

    // ---- CSR-build role ----
    const int o    = blockIdx.x;
    const int lane = t & 63;
    const int wv   = t >> 6;   // 0..7

    const float2 m = *reinterpret_cast<const float2*>(mask + o * IN_SZ + t * 2);
    const bool nx = (m.x != 0.0f);
    const bool ny = (m.y != 0.0f);
    const unsigned long long bx = __ballot(nx);
    const unsigned long long by = __ballot(ny);
    const unsigned long long mlow = ((unsigned long long)1 << lane) - 1;
    int off = __popcll(bx & mlow) + __popcll(by & mlow);
    if (lane == 0) s_wsum[wv] = __popcll(bx) + __popcll(by);
    __syncthreads();

    int base = 0, cnt = 0;
#pragma unroll
    for (int i = 0; i < 8; ++i) {
        int v = s_wsum[i];
        if (i < wv) base += v;
        cnt += v;
    }
    off += base;
    if (nx) s_idx[off]      = t * 2;
    if (ny) s_idx[off + nx] = t * 2 + 1;
    __syncthreads();

    for (int k = t; k < cnt; k += 512) g_idx[o * IDX_STRIDE + k] = s_idx[k];
    if (t == 0) g_cnt[o] = cnt;
}

// ---------------------------------------------------------------------------
// Kernel 2: pure gather-product. Block per o; stage the precompacted index
// list into LDS (one coalesced pass), then 4 k-slices x 128 batches with
// 2 independent accumulators per thread (ILP 2). Minimal critical path.
// ---------------------------------------------------------------------------
__global__ __launch_bounds__(512) void cn_gather(const float* __restrict__ xT,
                                                 const int* __restrict__ g_cnt,
                                                 const int* __restrict__ g_idx,
                                                 float* __restrict__ out) {
    __shared__ int   s_idx[IDX_STRIDE];
    __shared__ float s_part[4][B_SZ];
    __shared__ int   s_nz[4][B_SZ];

    const int o = blockIdx.x;
    const int t = threadIdx.x;
    const int cnt = g_cnt[o];   // block-uniform -> scalar load

    for (int k = t; k < cnt; k += 512) s_idx[k] = g_idx[o * IDX_STRIDE + k];
    __syncthreads();

    const int b = t & 127;   // batch
    const int s = t >> 7;    // k-slice 0..3 (wave-uniform)

    float p0 = 1.0f, p1 = 1.0f;
    int   a0 = 0,    a1 = 0;
    int k = s;
    for (; k + 4 < cnt; k += 8) {
        const float v0 = xT[s_idx[k]     * B_SZ + b];  // 64 lanes coalesced
        const float v1 = xT[s_idx[k + 4] * B_SZ + b];
        const bool n0 = (v0 != 0.0f), n1 = (v1 != 0.0f);
        p0 *= n0 ? v0 : 1.0f;  a0 |= n0;
        p1 *= n1 ? v1 : 1.0f;  a1 |= n1;
    }
    if (k < cnt) {
        const float v0 = xT[s_idx[k] * B_SZ + b];
        const bool n0 = (v0 != 0.0f);
        p0 *= n0 ? v0 : 1.0f;  a0 |= n0;
    }
    s_part[s][b] = p0 * p1;
    s_nz[s][b]   = a0 | a1;
    __syncthreads();

    if (t < B_SZ) {
        const float p = s_part[0][t] * s_part[1][t] * s_part[2][t] * s_part[3][t];
        const int   a = s_nz[0][t] | s_nz[1][t] | s_nz[2][t] | s_nz[3][t];
        out[t * OUT_SZ + o] = a ? p : 0.0f;
    }
}

// ---------------------------------------------------------------------------
extern "C" void kernel_launch(void* const* d_in, const int* in_sizes, int n_in,
                              void* d_out, int out_size, void* d_ws, size_t ws_size,
                              hipStream_t stream) {
    const float* x    = (const float*)d_in[0];
    const float* mask = (const float*)d_in[1];
    float*       out  = (float*)d_out;

    char* ws = (char*)d_ws;
    float* xT    = (float*)(ws);                       // 512 KB
    int*   g_cnt = (int*)(ws + (512 << 10));           // 4 KB
    int*   g_idx = (int*)(ws + (1 << 20));             // 4 MB

    prep<<<OUT_SZ + 128, 512, 0, stream>>>(x, mask, xT, g_cnt, g_idx);
    cn_gather<<<OUT_SZ, 512, 0, stream>>>(xT, g_cnt, g_idx, out);
}